// Round 6
// baseline (715.988 us; speedup 1.0000x reference)
//
#include <hip/hip_runtime.h>

#define NB 16384
#define ND 512
#define NH 128
#define NHH 256
#define NG 18

typedef short s8v __attribute__((ext_vector_type(8)));
typedef __bf16 bf8v __attribute__((ext_vector_type(8)));
typedef float f4v __attribute__((ext_vector_type(4)));
typedef unsigned int u4v __attribute__((ext_vector_type(4)));
typedef unsigned int u2v __attribute__((ext_vector_type(2)));

static __device__ __forceinline__ unsigned short f2bf(float f) {
  unsigned int u = __builtin_bit_cast(unsigned int, f);
  u += 0x7FFFu + ((u >> 16) & 1u);
  return (unsigned short)(u >> 16);
}

static __device__ __forceinline__ f4v mfma16(s8v a, s8v b, f4v c) {
  return __builtin_amdgcn_mfma_f32_16x16x32_bf16(
      __builtin_bit_cast(bf8v, a), __builtin_bit_cast(bf8v, b), c, 0, 0, 0);
}

// ---- weight transpose+convert: out[g][c][r] = bf16(in[g][r][c]) ----
__global__ __launch_bounds__(256) void k_transpose(const float* __restrict__ in,
                                                   unsigned short* __restrict__ out,
                                                   int R, int C) {
  __shared__ float t[64][65];
  const int g = blockIdx.y;
  const int nCt = C >> 6;
  const int tr = blockIdx.x / nCt;
  const int tc = blockIdx.x - tr * nCt;
  const int lw = threadIdx.x >> 6;
  const int lc = threadIdx.x & 63;
  const float* ip = in + (size_t)g * R * C + (size_t)(tr << 6) * C + (tc << 6);
#pragma unroll
  for (int i = 0; i < 16; ++i) {
    int r = (i << 2) + lw;
    t[r][lc] = ip[(size_t)r * C + lc];
  }
  __syncthreads();
  unsigned short* op = out + (size_t)g * R * C + (size_t)(tc << 6) * R + (tr << 6);
#pragma unroll
  for (int i = 0; i < 16; ++i) {
    int r = (i << 2) + lw;
    op[(size_t)r * R + lc] = f2bf(t[lc][r]);
  }
}

// Wa [512][18] -> WaT [18][512] f32
__global__ __launch_bounds__(256) void k_wat(const float* __restrict__ wa,
                                             float* __restrict__ wat) {
  int tid = blockIdx.x * 256 + threadIdx.x;
  if (tid < NG * ND) {
    int g = tid >> 9, d = tid & (ND - 1);
    wat[tid] = wa[d * NG + g];
  }
}

// attention weights w[B,G] = softmax(X@Wa+ba)*gv, plus X -> bf16
__global__ __launch_bounds__(256) void k_attn(const float* __restrict__ X,
                                              const float* __restrict__ GV,
                                              const float* __restrict__ wat,
                                              const float* __restrict__ ba,
                                              float* __restrict__ w,
                                              unsigned short* __restrict__ xb) {
  __shared__ float wl[NG * ND];
  const int tid = threadIdx.x;
  for (int i = tid; i < NG * ND; i += 256) wl[i] = wat[i];
  __syncthreads();
  const int lane = tid & 63;
  const int row = (blockIdx.x << 2) + (tid >> 6);
  const float* xr = X + (size_t)row * ND + (lane << 3);
  float x[8];
  {
    float4 a = *(const float4*)xr;
    float4 b = *(const float4*)(xr + 4);
    x[0] = a.x; x[1] = a.y; x[2] = a.z; x[3] = a.w;
    x[4] = b.x; x[5] = b.y; x[6] = b.z; x[7] = b.w;
  }
  {
    u4v p;
#pragma unroll
    for (int j = 0; j < 4; ++j)
      p[j] = (unsigned)f2bf(x[2 * j]) | ((unsigned)f2bf(x[2 * j + 1]) << 16);
    *(u4v*)(xb + (size_t)row * ND + (lane << 3)) = p;
  }
  float lg[NG];
#pragma unroll
  for (int g = 0; g < NG; ++g) {
    const float* wr = wl + g * ND + (lane << 3);
    float s = 0.f;
#pragma unroll
    for (int j = 0; j < 8; ++j) s += x[j] * wr[j];
    lg[g] = s;
  }
#pragma unroll
  for (int off = 32; off > 0; off >>= 1) {
#pragma unroll
    for (int g = 0; g < NG; ++g) lg[g] += __shfl_xor(lg[g], off);
  }
  float m = -3.4e38f;
#pragma unroll
  for (int g = 0; g < NG; ++g) { lg[g] += ba[g]; m = fmaxf(m, lg[g]); }
  float s = 0.f;
#pragma unroll
  for (int g = 0; g < NG; ++g) { lg[g] = expf(lg[g] - m); s += lg[g]; }
  float inv = 1.f / s;
  if (lane < NG) {
    float gv = GV[(size_t)row * NG + lane];
    w[(size_t)row * NG + lane] = gv > 0.f ? lg[lane] * inv * gv : 0.f;
  }
}

// experts, genre-split. 1 block = 128 rows x 9 genres, 8 waves, 1 block/CU.
// Partial refinements (f32) parked in out[:, gh*128 .. gh*128+127].
__global__ __launch_bounds__(512, 2) void k_expert(
    const unsigned short* __restrict__ xb,    // [B][512] bf16
    const float* __restrict__ wbg,            // [B][18]
    const unsigned short* __restrict__ w1t,   // [18][256][512] bf16
    const unsigned short* __restrict__ w2t,   // [18][128][256]
    const unsigned short* __restrict__ w3t,   // [18][128][128]
    const float* __restrict__ b1, const float* __restrict__ b2,
    const float* __restrict__ b3,
    float* __restrict__ scratch) {            // = out, cols 0..255 as f32 scratch
  __shared__ __align__(16) char smem[108544];
  char* const H1 = smem;                      // [128][256] bf16, stride 512B, swz
  char* const H2 = smem + 65536;              // [128][128] bf16, stride 256B, swz
  float* const WL = (float*)(smem + 98304);   // [128][20]

  const int tid = threadIdx.x;
  const int rt = blockIdx.x >> 1;
  const int gh = blockIdx.x & 1;
  const int row0 = rt << 7;
  const int g0 = gh * 9;

  for (int i = tid; i < 128 * NG; i += 512) {
    int r = i / NG, g = i - r * NG;
    WL[r * 20 + g] = wbg[(size_t)(row0 + r) * NG + g];
  }
  __syncthreads();

  const int wid = tid >> 6, lane = tid & 63;
  const int lr = lane & 15, lk = lane >> 4;
  const int c1 = wid << 5;   // G1 col base (8 waves x 32 = 256)
  const int c2 = wid << 4;   // G2/G3 col base (8 waves x 16 = 128)

#define LDH1(row, ks) \
  (*(const s8v*)(H1 + ((((row) << 9) + ((ks) << 6) + (lk << 4)) ^ (((row) & 7) << 4))))
#define LDH2(row, ks) \
  (*(const s8v*)(H2 + ((((row) << 8) + ((ks) << 6) + (lk << 4)) ^ (((row) & 7) << 4))))

  // global A base: rows row0+lr (+16*mi), 16B chunks at lk*8 elems
  const unsigned short* const ap = xb + ((size_t)(row0 + lr) << 9) + (lk << 3);

  f4v racc[8];
#pragma unroll
  for (int i = 0; i < 8; ++i) racc[i] = (f4v){0.f, 0.f, 0.f, 0.f};

  for (int gi = 0; gi < 9; ++gi) {
    const int g = g0 + gi;
    // ---------- GEMM1: h1 = relu(X @ W1[g] + b1[g])  [128,256] ----------
    const unsigned short* const w1g = w1t + (size_t)g * (NHH * ND);
    const unsigned short* const bp0 = w1g + ((size_t)(c1 + lr) << 9) + (lk << 3);
    const unsigned short* const bp1 = w1g + ((size_t)(c1 + 16 + lr) << 9) + (lk << 3);
    const float bv1a = b1[g * NHH + c1 + lr];
    const float bv1b = b1[g * NHH + c1 + 16 + lr];
    f4v acc1[8][2];
#pragma unroll
    for (int mi = 0; mi < 8; ++mi) {
      acc1[mi][0] = (f4v){0.f, 0.f, 0.f, 0.f};
      acc1[mi][1] = (f4v){0.f, 0.f, 0.f, 0.f};
    }
#pragma unroll 2
    for (int ks = 0; ks < 16; ++ks) {
      s8v b0 = *(const s8v*)(bp0 + (ks << 5));
      s8v b1v = *(const s8v*)(bp1 + (ks << 5));
      s8v a[8];
#pragma unroll
      for (int mi = 0; mi < 8; ++mi)
        a[mi] = *(const s8v*)(ap + ((size_t)mi << 13) + (ks << 5));
#pragma unroll
      for (int mi = 0; mi < 8; ++mi) {
        acc1[mi][0] = mfma16(a[mi], b0, acc1[mi][0]);
        acc1[mi][1] = mfma16(a[mi], b1v, acc1[mi][1]);
      }
    }
#pragma unroll
    for (int mi = 0; mi < 8; ++mi)
#pragma unroll
      for (int ni = 0; ni < 2; ++ni)
#pragma unroll
        for (int r = 0; r < 4; ++r) {
          const int row = (mi << 4) + (lk << 2) + r;
          const int col = c1 + (ni << 4) + lr;
          float v = fmaxf(acc1[mi][ni][r] + (ni ? bv1b : bv1a), 0.f);
          const int byte = (row << 9) + (col << 1);
          *(unsigned short*)(H1 + (byte ^ ((row & 7) << 4))) = f2bf(v);
        }
    // hoist GEMM2 B-fragments + bias (latency hides under barrier)
    const unsigned short* const w2g = w2t + (size_t)g * (NH * NHH);
    const unsigned short* const bp2 = w2g + ((size_t)(c2 + lr) << 8) + (lk << 3);
    s8v b2f[8];
#pragma unroll
    for (int ks = 0; ks < 8; ++ks) b2f[ks] = *(const s8v*)(bp2 + (ks << 5));
    const float bv2 = b2[g * NH + c2 + lr];
    __syncthreads();

    // ---------- GEMM2: h2 = relu(h1 @ W2[g] + b2[g])  [128,128] ----------
    f4v acc2[8];
#pragma unroll
    for (int mi = 0; mi < 8; ++mi) acc2[mi] = (f4v){0.f, 0.f, 0.f, 0.f};
#pragma unroll
    for (int ks = 0; ks < 8; ++ks) {
      s8v a[8];
#pragma unroll
      for (int mi = 0; mi < 8; ++mi) a[mi] = LDH1((mi << 4) + lr, ks);
#pragma unroll
      for (int mi = 0; mi < 8; ++mi) acc2[mi] = mfma16(a[mi], b2f[ks], acc2[mi]);
    }
#pragma unroll
    for (int mi = 0; mi < 8; ++mi)
#pragma unroll
      for (int r = 0; r < 4; ++r) {
        const int row = (mi << 4) + (lk << 2) + r;
        const int col = c2 + lr;
        float v = fmaxf(acc2[mi][r] + bv2, 0.f);
        const int byte = (row << 8) + (col << 1);
        *(unsigned short*)(H2 + (byte ^ ((row & 7) << 4))) = f2bf(v);
      }
    // hoist GEMM3 B-fragments + bias
    const unsigned short* const w3g = w3t + (size_t)g * (NH * NH);
    const unsigned short* const bp3 = w3g + ((size_t)(c2 + lr) << 7) + (lk << 3);
    s8v b3f[4];
#pragma unroll
    for (int ks = 0; ks < 4; ++ks) b3f[ks] = *(const s8v*)(bp3 + (ks << 5));
    const float bv3 = b3[g * NH + c2 + lr];
    __syncthreads();

    // ---------- GEMM3: h3 = h2 @ W3[g] + b3[g]; racc += w*h3 ----------
    f4v acc3[8];
#pragma unroll
    for (int mi = 0; mi < 8; ++mi) acc3[mi] = (f4v){0.f, 0.f, 0.f, 0.f};
#pragma unroll
    for (int ks = 0; ks < 4; ++ks) {
      s8v a[8];
#pragma unroll
      for (int mi = 0; mi < 8; ++mi) a[mi] = LDH2((mi << 4) + lr, ks);
#pragma unroll
      for (int mi = 0; mi < 8; ++mi) acc3[mi] = mfma16(a[mi], b3f[ks], acc3[mi]);
    }
#pragma unroll
    for (int mi = 0; mi < 8; ++mi)
#pragma unroll
      for (int r = 0; r < 4; ++r) {
        const int row = (mi << 4) + (lk << 2) + r;
        racc[mi][r] += WL[row * 20 + g] * (acc3[mi][r] + bv3);
      }
  }

  // write partial refinement (f32) into out-scratch cols gh*128 + [0,128)
#pragma unroll
  for (int mi = 0; mi < 8; ++mi)
#pragma unroll
    for (int r = 0; r < 4; ++r) {
      const int row = (mi << 4) + (lk << 2) + r;
      scratch[((size_t)(row0 + row) << 9) + (gh << 7) + c2 + lr] = racc[mi][r];
    }
#undef LDH1
#undef LDH2
}

// aggregation: out = relu([X | ref] @ Wagg + bagg). 1 block = 32 rows, full N.
__global__ __launch_bounds__(512, 2) void k_agg(
    const unsigned short* __restrict__ xb,    // [B][512] bf16
    const unsigned short* __restrict__ waggt, // [512][640] bf16
    const float* __restrict__ bagg,
    float* __restrict__ out) {
  __shared__ __align__(16) char RB[8192];     // [32][128] bf16, stride 256B, swz
  const int tid = threadIdx.x;
  const int row0 = blockIdx.x << 5;

  // stage ref = partial0 + partial1 (f32 in out cols 0..255) -> bf16 LDS
#pragma unroll
  for (int i = 0; i < 2; ++i) {
    int e = (i << 9) + tid;   // 0..1023
    int r = e >> 5;           // 0..31
    int q = e & 31;           // float4 col index (0..31 -> cols 4q..4q+3)
    const float4* o4 = (const float4*)out + (((size_t)(row0 + r)) << 7);
    float4 p0 = o4[q];
    float4 p1 = o4[32 + q];
    unsigned int u0 = (unsigned)f2bf(p0.x + p1.x) | ((unsigned)f2bf(p0.y + p1.y) << 16);
    unsigned int u1 = (unsigned)f2bf(p0.z + p1.z) | ((unsigned)f2bf(p0.w + p1.w) << 16);
    u2v uv; uv[0] = u0; uv[1] = u1;
    int byte = (r << 8) + (q << 3);
    *(u2v*)(RB + (byte ^ ((r & 7) << 4))) = uv;
  }
  __syncthreads();

  const int wid = tid >> 6, lane = tid & 63;
  const int lr = lane & 15, lk = lane >> 4;
  const int c4 = wid << 6;   // 8 waves x 64 cols = 512

  float bv4[4];
#pragma unroll
  for (int ni = 0; ni < 4; ++ni) bv4[ni] = bagg[c4 + (ni << 4) + lr];
  const unsigned short* bp4[4];
#pragma unroll
  for (int ni = 0; ni < 4; ++ni)
    bp4[ni] = waggt + (size_t)(c4 + (ni << 4) + lr) * 640 + (lk << 3);
  const unsigned short* const ap = xb + ((size_t)(row0 + lr) << 9) + (lk << 3);

  f4v acc4[2][4];
#pragma unroll
  for (int mi = 0; mi < 2; ++mi)
#pragma unroll
    for (int ni = 0; ni < 4; ++ni) acc4[mi][ni] = (f4v){0.f, 0.f, 0.f, 0.f};

#pragma unroll 4
  for (int ks = 0; ks < 16; ++ks) {
    s8v a0 = *(const s8v*)(ap + (ks << 5));
    s8v a1 = *(const s8v*)(ap + (1 << 13) + (ks << 5));
    s8v bb[4];
#pragma unroll
    for (int ni = 0; ni < 4; ++ni) bb[ni] = *(const s8v*)(bp4[ni] + (ks << 5));
#pragma unroll
    for (int ni = 0; ni < 4; ++ni) {
      acc4[0][ni] = mfma16(a0, bb[ni], acc4[0][ni]);
      acc4[1][ni] = mfma16(a1, bb[ni], acc4[1][ni]);
    }
  }
#pragma unroll
  for (int kh = 0; kh < 4; ++kh) {
    s8v a0, a1;
    {
      int row = lr;
      a0 = *(const s8v*)(RB + (((row << 8) + (kh << 6) + (lk << 4)) ^ ((row & 7) << 4)));
      row = 16 + lr;
      a1 = *(const s8v*)(RB + (((row << 8) + (kh << 6) + (lk << 4)) ^ ((row & 7) << 4)));
    }
    s8v bb[4];
#pragma unroll
    for (int ni = 0; ni < 4; ++ni)
      bb[ni] = *(const s8v*)(bp4[ni] + ((16 + kh) << 5));
#pragma unroll
    for (int ni = 0; ni < 4; ++ni) {
      acc4[0][ni] = mfma16(a0, bb[ni], acc4[0][ni]);
      acc4[1][ni] = mfma16(a1, bb[ni], acc4[1][ni]);
    }
  }
#pragma unroll
  for (int mi = 0; mi < 2; ++mi)
#pragma unroll
    for (int ni = 0; ni < 4; ++ni)
#pragma unroll
      for (int r = 0; r < 4; ++r) {
        const int row = (mi << 4) + (lk << 2) + r;
        const int col = c4 + (ni << 4) + lr;
        float v = acc4[mi][ni][r] + bv4[ni];
        out[((size_t)(row0 + row) << 9) + col] = fmaxf(v, 0.f);
      }
}

// ---------------- workspace layout (bytes) ----------------
#define OFF_W     0u          // w[B][18] f32        : 1179648
#define OFF_XB    1179648u    // xb[B][512] bf16     : 16777216
#define OFF_W1T   17956864u   // [18][256][512] bf16 : 4718592
#define OFF_W2T   22675456u   // [18][128][256] bf16 : 1179648
#define OFF_W3T   23855104u   // [18][128][128] bf16 : 589824
#define OFF_WAGGT 24444928u   // [512][640] bf16     : 655360
#define OFF_WAT   25100288u   // [18][512] f32       : 36864  (end 25137152)

extern "C" void kernel_launch(void* const* d_in, const int* in_sizes, int n_in,
                              void* d_out, int out_size, void* d_ws, size_t ws_size,
                              hipStream_t stream) {
  const float* X    = (const float*)d_in[0];
  const float* GV   = (const float*)d_in[1];
  const float* W1   = (const float*)d_in[2];
  const float* b1   = (const float*)d_in[3];
  const float* W2   = (const float*)d_in[4];
  const float* b2   = (const float*)d_in[5];
  const float* W3   = (const float*)d_in[6];
  const float* b3   = (const float*)d_in[7];
  const float* Wa   = (const float*)d_in[8];
  const float* ba   = (const float*)d_in[9];
  const float* Wagg = (const float*)d_in[10];
  const float* bagg = (const float*)d_in[11];
  float* out = (float*)d_out;
  char* ws = (char*)d_ws;

  float* w_ws           = (float*)(ws + OFF_W);
  unsigned short* xb    = (unsigned short*)(ws + OFF_XB);
  unsigned short* w1t   = (unsigned short*)(ws + OFF_W1T);
  unsigned short* w2t   = (unsigned short*)(ws + OFF_W2T);
  unsigned short* w3t   = (unsigned short*)(ws + OFF_W3T);
  unsigned short* waggt = (unsigned short*)(ws + OFF_WAGGT);
  float* wat            = (float*)(ws + OFF_WAT);

  k_transpose<<<dim3(32, 18), 256, 0, stream>>>(W1, w1t, 512, 256);
  k_transpose<<<dim3(8, 18), 256, 0, stream>>>(W2, w2t, 256, 128);
  k_transpose<<<dim3(4, 18), 256, 0, stream>>>(W3, w3t, 128, 128);
  k_transpose<<<dim3(80, 1), 256, 0, stream>>>(Wagg, waggt, 640, 512);
  k_wat<<<36, 256, 0, stream>>>(Wa, wat);
  k_attn<<<4096, 256, 0, stream>>>(X, GV, wat, ba, w_ws, xb);
  k_expert<<<256, 512, 0, stream>>>(xb, w_ws, w1t, w2t, w3t, b1, b2, b3, out);
  k_agg<<<512, 512, 0, stream>>>(xb, waggt, bagg, out);
}

// Round 7
// 290.239 us; speedup vs baseline: 2.4669x; 2.4669x over previous
//
#include <hip/hip_runtime.h>

#define NB 16384
#define ND 512
#define NH 128
#define NHH 256
#define NG 18

typedef short s8v __attribute__((ext_vector_type(8)));
typedef __bf16 bf8v __attribute__((ext_vector_type(8)));
typedef float f4v __attribute__((ext_vector_type(4)));
typedef unsigned int u4v __attribute__((ext_vector_type(4)));

static __device__ __forceinline__ unsigned short f2bf(float f) {
  unsigned int u = __builtin_bit_cast(unsigned int, f);
  u += 0x7FFFu + ((u >> 16) & 1u);
  return (unsigned short)(u >> 16);
}

static __device__ __forceinline__ f4v mfma16(s8v a, s8v b, f4v c) {
  return __builtin_amdgcn_mfma_f32_16x16x32_bf16(
      __builtin_bit_cast(bf8v, a), __builtin_bit_cast(bf8v, b), c, 0, 0, 0);
}

// ---- weight transpose+convert: out[g][c][r] = bf16(in[g][r][c]) ----
__global__ __launch_bounds__(256) void k_transpose(const float* __restrict__ in,
                                                   unsigned short* __restrict__ out,
                                                   int R, int C) {
  __shared__ float t[64][65];
  const int g = blockIdx.y;
  const int nCt = C >> 6;
  const int tr = blockIdx.x / nCt;
  const int tc = blockIdx.x - tr * nCt;
  const int lw = threadIdx.x >> 6;
  const int lc = threadIdx.x & 63;
  const float* ip = in + (size_t)g * R * C + (size_t)(tr << 6) * C + (tc << 6);
#pragma unroll
  for (int i = 0; i < 16; ++i) {
    int r = (i << 2) + lw;
    t[r][lc] = ip[(size_t)r * C + lc];
  }
  __syncthreads();
  unsigned short* op = out + (size_t)g * R * C + (size_t)(tc << 6) * R + (tr << 6);
#pragma unroll
  for (int i = 0; i < 16; ++i) {
    int r = (i << 2) + lw;
    op[(size_t)r * R + lc] = f2bf(t[lc][r]);
  }
}

// Wa [512][18] -> WaT [18][512] f32
__global__ __launch_bounds__(256) void k_wat(const float* __restrict__ wa,
                                             float* __restrict__ wat) {
  int tid = blockIdx.x * 256 + threadIdx.x;
  if (tid < NG * ND) {
    int g = tid >> 9, d = tid & (ND - 1);
    wat[tid] = wa[d * NG + g];
  }
}

// attention weights w[B,G] = softmax(X@Wa+ba)*gv, plus X -> bf16
__global__ __launch_bounds__(256) void k_attn(const float* __restrict__ X,
                                              const float* __restrict__ GV,
                                              const float* __restrict__ wat,
                                              const float* __restrict__ ba,
                                              float* __restrict__ w,
                                              unsigned short* __restrict__ xb) {
  __shared__ float wl[NG * ND];
  const int tid = threadIdx.x;
  for (int i = tid; i < NG * ND; i += 256) wl[i] = wat[i];
  __syncthreads();
  const int lane = tid & 63;
  const int row = (blockIdx.x << 2) + (tid >> 6);
  const float* xr = X + (size_t)row * ND + (lane << 3);
  float x[8];
  {
    float4 a = *(const float4*)xr;
    float4 b = *(const float4*)(xr + 4);
    x[0] = a.x; x[1] = a.y; x[2] = a.z; x[3] = a.w;
    x[4] = b.x; x[5] = b.y; x[6] = b.z; x[7] = b.w;
  }
  {
    u4v p;
#pragma unroll
    for (int j = 0; j < 4; ++j)
      p[j] = (unsigned)f2bf(x[2 * j]) | ((unsigned)f2bf(x[2 * j + 1]) << 16);
    *(u4v*)(xb + (size_t)row * ND + (lane << 3)) = p;
  }
  float lg[NG];
#pragma unroll
  for (int g = 0; g < NG; ++g) {
    const float* wr = wl + g * ND + (lane << 3);
    float s = 0.f;
#pragma unroll
    for (int j = 0; j < 8; ++j) s += x[j] * wr[j];
    lg[g] = s;
  }
#pragma unroll
  for (int off = 32; off > 0; off >>= 1) {
#pragma unroll
    for (int g = 0; g < NG; ++g) lg[g] += __shfl_xor(lg[g], off);
  }
  float m = -3.4e38f;
#pragma unroll
  for (int g = 0; g < NG; ++g) { lg[g] += ba[g]; m = fmaxf(m, lg[g]); }
  float s = 0.f;
#pragma unroll
  for (int g = 0; g < NG; ++g) { lg[g] = expf(lg[g] - m); s += lg[g]; }
  float inv = 1.f / s;
  if (lane < NG) {
    float gv = GV[(size_t)row * NG + lane];
    w[(size_t)row * NG + lane] = gv > 0.f ? lg[lane] * inv * gv : 0.f;
  }
}

// fused experts + aggregation. 1 block = 64 rows, 8 waves.
// B-latency plan: GEMM2/3 B fully reg-hoisted across the preceding barrier;
// GEMM1/GEMM4 depth-1 B prefetch; A always fresh from LDS (low reg pressure).
__global__ __launch_bounds__(512, 2) void k_main(
    const unsigned short* __restrict__ xb,    // [B][512] bf16
    const float* __restrict__ wbg,            // [B][18]
    const unsigned short* __restrict__ w1t,   // [18][256][512] bf16
    const unsigned short* __restrict__ w2t,   // [18][128][256]
    const unsigned short* __restrict__ w3t,   // [18][128][128]
    const unsigned short* __restrict__ waggt, // [512][640]
    const float* __restrict__ b1, const float* __restrict__ b2,
    const float* __restrict__ b3, const float* __restrict__ bagg,
    float* __restrict__ out) {
  __shared__ __align__(16) char smem[119808];
  char* const XT = smem;                 // [64][512] bf16, stride 1024B, swz
  char* const H1 = smem + 65536;         // [64][256] bf16, stride 512B, swz
  char* const H2 = smem + 98304;         // [64][128] bf16, stride 256B, swz
  float* const WL = (float*)(smem + 114688); // [64][20]

  const int tid = threadIdx.x;
  const int row0 = blockIdx.x << 6;

#pragma unroll
  for (int i = 0; i < 8; ++i) {
    int idx = (i << 9) + tid;
    int r = idx >> 6, c16 = idx & 63;
    u4v v = *(const u4v*)(xb + ((size_t)(row0 + r) << 9) + (c16 << 3));
    int byte = (r << 10) + (c16 << 4);
    *(u4v*)(XT + (byte ^ ((r & 7) << 4))) = v;
  }
  for (int i = tid; i < 64 * NG; i += 512) {
    int r = i / NG, g = i - r * NG;
    WL[r * 20 + g] = wbg[(size_t)(row0 + r) * NG + g];
  }

  const int wid = tid >> 6, lane = tid & 63;
  const int lr = lane & 15, lk = lane >> 4;
  const int c1 = wid << 5;            // GEMM1 col base (8 x 32 = 256)
  const int c2 = wid << 4;            // GEMM2/3 col base (8 x 16 = 128)
  const int c4 = wid << 6;            // GEMM4 col base (8 x 64 = 512)

  // per-wave B base pointers (genre 0 offsets applied in-loop)
  const unsigned short* const bp10 = w1t + ((size_t)(c1 + lr) << 9) + (lk << 3);
  const unsigned short* const bp11 = w1t + ((size_t)(c1 + 16 + lr) << 9) + (lk << 3);
  const unsigned short* const bp2b = w2t + ((size_t)(c2 + lr) << 8) + (lk << 3);
  const unsigned short* const bp3b = w3t + ((size_t)(c2 + lr) << 7) + (lk << 3);

  // prefetch GEMM1 g=0 ks=0 B (drains under the staging barrier)
  s8v nx10 = *(const s8v*)bp10;
  s8v nx11 = *(const s8v*)bp11;

  __syncthreads();

#define LDXT(row, ks) \
  (*(const s8v*)(XT + ((((row) << 10) + ((ks) << 6) + (lk << 4)) ^ (((row) & 7) << 4))))
#define LDH1(row, ks) \
  (*(const s8v*)(H1 + ((((row) << 9) + ((ks) << 6) + (lk << 4)) ^ (((row) & 7) << 4))))
#define LDH2(row, ks) \
  (*(const s8v*)(H2 + ((((row) << 8) + ((ks) << 6) + (lk << 4)) ^ (((row) & 7) << 4))))

  f4v racc[4];
#pragma unroll
  for (int i = 0; i < 4; ++i) racc[i] = (f4v){0.f, 0.f, 0.f, 0.f};

  for (int g = 0; g < NG; ++g) {
    const size_t o1 = (size_t)g * (NHH * ND);
    // ---------- GEMM1: h1 = relu(X @ W1[g] + b1[g])  [64,256] ----------
    const float bv1a = b1[g * NHH + c1 + lr];
    const float bv1b = b1[g * NHH + c1 + 16 + lr];
    f4v acc1[4][2];
#pragma unroll
    for (int mi = 0; mi < 4; ++mi) {
      acc1[mi][0] = (f4v){0.f, 0.f, 0.f, 0.f};
      acc1[mi][1] = (f4v){0.f, 0.f, 0.f, 0.f};
    }
    {
      s8v bc0 = nx10, bc1 = nx11;
#pragma unroll
      for (int ks = 0; ks < 16; ++ks) {
        s8v bn0, bn1;
        if (ks < 15) {
          bn0 = *(const s8v*)(bp10 + o1 + ((ks + 1) << 5));
          bn1 = *(const s8v*)(bp11 + o1 + ((ks + 1) << 5));
        }
        s8v a0 = LDXT(lr, ks);
        s8v a1 = LDXT(16 + lr, ks);
        s8v a2 = LDXT(32 + lr, ks);
        s8v a3 = LDXT(48 + lr, ks);
        acc1[0][0] = mfma16(a0, bc0, acc1[0][0]);
        acc1[0][1] = mfma16(a0, bc1, acc1[0][1]);
        acc1[1][0] = mfma16(a1, bc0, acc1[1][0]);
        acc1[1][1] = mfma16(a1, bc1, acc1[1][1]);
        acc1[2][0] = mfma16(a2, bc0, acc1[2][0]);
        acc1[2][1] = mfma16(a2, bc1, acc1[2][1]);
        acc1[3][0] = mfma16(a3, bc0, acc1[3][0]);
        acc1[3][1] = mfma16(a3, bc1, acc1[3][1]);
        if (ks < 15) { bc0 = bn0; bc1 = bn1; }
      }
    }
#pragma unroll
    for (int mi = 0; mi < 4; ++mi)
#pragma unroll
      for (int ni = 0; ni < 2; ++ni)
#pragma unroll
        for (int r = 0; r < 4; ++r) {
          const int row = (mi << 4) + (lk << 2) + r;
          const int col = c1 + (ni << 4) + lr;
          float v = fmaxf(acc1[mi][ni][r] + (ni ? bv1b : bv1a), 0.f);
          const int byte = (row << 9) + (col << 1);
          *(unsigned short*)(H1 + (byte ^ ((row & 7) << 4))) = f2bf(v);
        }
    // hoist ALL GEMM2 B-fragments + bias across the barrier
    const unsigned short* const bp2 = bp2b + (size_t)g * (NH * NHH);
    s8v b2f[8];
#pragma unroll
    for (int ks = 0; ks < 8; ++ks) b2f[ks] = *(const s8v*)(bp2 + (ks << 5));
    const float bv2 = b2[g * NH + c2 + lr];
    __syncthreads();

    // ---------- GEMM2: h2 = relu(h1 @ W2[g] + b2[g])  [64,128], n=16/wave ----
    f4v acc2[4];
#pragma unroll
    for (int mi = 0; mi < 4; ++mi) acc2[mi] = (f4v){0.f, 0.f, 0.f, 0.f};
#pragma unroll
    for (int ks = 0; ks < 8; ++ks) {
      s8v a0 = LDH1(lr, ks);
      s8v a1 = LDH1(16 + lr, ks);
      s8v a2 = LDH1(32 + lr, ks);
      s8v a3 = LDH1(48 + lr, ks);
      acc2[0] = mfma16(a0, b2f[ks], acc2[0]);
      acc2[1] = mfma16(a1, b2f[ks], acc2[1]);
      acc2[2] = mfma16(a2, b2f[ks], acc2[2]);
      acc2[3] = mfma16(a3, b2f[ks], acc2[3]);
    }
#pragma unroll
    for (int mi = 0; mi < 4; ++mi)
#pragma unroll
      for (int r = 0; r < 4; ++r) {
        const int row = (mi << 4) + (lk << 2) + r;
        const int col = c2 + lr;
        float v = fmaxf(acc2[mi][r] + bv2, 0.f);
        const int byte = (row << 8) + (col << 1);
        *(unsigned short*)(H2 + (byte ^ ((row & 7) << 4))) = f2bf(v);
      }
    // hoist ALL GEMM3 B-fragments + bias across the barrier
    const unsigned short* const bp3 = bp3b + (size_t)g * (NH * NH);
    s8v b3f[4];
#pragma unroll
    for (int ks = 0; ks < 4; ++ks) b3f[ks] = *(const s8v*)(bp3 + (ks << 5));
    const float bv3 = b3[g * NH + c2 + lr];
    __syncthreads();

    // ---------- GEMM3: h3 = h2 @ W3[g] + b3[g]; racc += w*h3, n=16/wave -----
    f4v acc3[4];
#pragma unroll
    for (int mi = 0; mi < 4; ++mi) acc3[mi] = (f4v){0.f, 0.f, 0.f, 0.f};
#pragma unroll
    for (int ks = 0; ks < 4; ++ks) {
      s8v a0 = LDH2(lr, ks);
      s8v a1 = LDH2(16 + lr, ks);
      s8v a2 = LDH2(32 + lr, ks);
      s8v a3 = LDH2(48 + lr, ks);
      acc3[0] = mfma16(a0, b3f[ks], acc3[0]);
      acc3[1] = mfma16(a1, b3f[ks], acc3[1]);
      acc3[2] = mfma16(a2, b3f[ks], acc3[2]);
      acc3[3] = mfma16(a3, b3f[ks], acc3[3]);
    }
    // prefetch next genre's GEMM1 ks=0 B (no barrier between GEMM3 and GEMM1)
    if (g + 1 < NG) {
      const size_t o1n = (size_t)(g + 1) * (NHH * ND);
      nx10 = *(const s8v*)(bp10 + o1n);
      nx11 = *(const s8v*)(bp11 + o1n);
    }
#pragma unroll
    for (int mi = 0; mi < 4; ++mi)
#pragma unroll
      for (int r = 0; r < 4; ++r) {
        const int row = (mi << 4) + (lk << 2) + r;
        racc[mi][r] += WL[row * 20 + g] * (acc3[mi][r] + bv3);
      }
  }

  // ---------- GEMM4: out = relu([X | ref] @ Wagg + bagg)  [64,512] ----------
  const unsigned short* bp4[4];
#pragma unroll
  for (int ni = 0; ni < 4; ++ni)
    bp4[ni] = waggt + (size_t)(c4 + (ni << 4) + lr) * 640 + (lk << 3);
  s8v g4b[4];
#pragma unroll
  for (int ni = 0; ni < 4; ++ni) g4b[ni] = *(const s8v*)bp4[ni];

  __syncthreads();  // all GEMM3 H2 reads done before overwrite with ref
#pragma unroll
  for (int mi = 0; mi < 4; ++mi)
#pragma unroll
    for (int r = 0; r < 4; ++r) {
      const int row = (mi << 4) + (lk << 2) + r;
      const int col = c2 + lr;
      const int byte = (row << 8) + (col << 1);
      *(unsigned short*)(H2 + (byte ^ ((row & 7) << 4))) = f2bf(racc[mi][r]);
    }
  __syncthreads();

  float bv4[4];
#pragma unroll
  for (int ni = 0; ni < 4; ++ni) bv4[ni] = bagg[c4 + (ni << 4) + lr];
  f4v acc4[4][4];
#pragma unroll
  for (int mi = 0; mi < 4; ++mi)
#pragma unroll
    for (int ni = 0; ni < 4; ++ni) acc4[mi][ni] = (f4v){0.f, 0.f, 0.f, 0.f};
  {
    s8v bc[4];
#pragma unroll
    for (int ni = 0; ni < 4; ++ni) bc[ni] = g4b[ni];
#pragma unroll
    for (int ks = 0; ks < 20; ++ks) {
      s8v bn[4];
      if (ks < 19) {
#pragma unroll
        for (int ni = 0; ni < 4; ++ni)
          bn[ni] = *(const s8v*)(bp4[ni] + ((ks + 1) << 5));
      }
      s8v a0, a1, a2, a3;
      if (ks < 16) {
        a0 = LDXT(lr, ks);
        a1 = LDXT(16 + lr, ks);
        a2 = LDXT(32 + lr, ks);
        a3 = LDXT(48 + lr, ks);
      } else {
        a0 = LDH2(lr, ks - 16);
        a1 = LDH2(16 + lr, ks - 16);
        a2 = LDH2(32 + lr, ks - 16);
        a3 = LDH2(48 + lr, ks - 16);
      }
#pragma unroll
      for (int ni = 0; ni < 4; ++ni) {
        acc4[0][ni] = mfma16(a0, bc[ni], acc4[0][ni]);
        acc4[1][ni] = mfma16(a1, bc[ni], acc4[1][ni]);
        acc4[2][ni] = mfma16(a2, bc[ni], acc4[2][ni]);
        acc4[3][ni] = mfma16(a3, bc[ni], acc4[3][ni]);
      }
      if (ks < 19) {
#pragma unroll
        for (int ni = 0; ni < 4; ++ni) bc[ni] = bn[ni];
      }
    }
  }
#pragma unroll
  for (int mi = 0; mi < 4; ++mi)
#pragma unroll
    for (int ni = 0; ni < 4; ++ni)
#pragma unroll
      for (int r = 0; r < 4; ++r) {
        const int row = (mi << 4) + (lk << 2) + r;
        const int col = c4 + (ni << 4) + lr;
        float v = acc4[mi][ni][r] + bv4[ni];
        out[((size_t)(row0 + row) << 9) + col] = fmaxf(v, 0.f);
      }
#undef LDXT
#undef LDH1
#undef LDH2
}

// ---------------- workspace layout (bytes) ----------------
#define OFF_W     0u          // w[B][18] f32        : 1179648
#define OFF_XB    1179648u    // xb[B][512] bf16     : 16777216
#define OFF_W1T   17956864u   // [18][256][512] bf16 : 4718592
#define OFF_W2T   22675456u   // [18][128][256] bf16 : 1179648
#define OFF_W3T   23855104u   // [18][128][128] bf16 : 589824
#define OFF_WAGGT 24444928u   // [512][640] bf16     : 655360
#define OFF_WAT   25100288u   // [18][512] f32       : 36864  (end 25137152)

extern "C" void kernel_launch(void* const* d_in, const int* in_sizes, int n_in,
                              void* d_out, int out_size, void* d_ws, size_t ws_size,
                              hipStream_t stream) {
  const float* X    = (const float*)d_in[0];
  const float* GV   = (const float*)d_in[1];
  const float* W1   = (const float*)d_in[2];
  const float* b1   = (const float*)d_in[3];
  const float* W2   = (const float*)d_in[4];
  const float* b2   = (const float*)d_in[5];
  const float* W3   = (const float*)d_in[6];
  const float* b3   = (const float*)d_in[7];
  const float* Wa   = (const float*)d_in[8];
  const float* ba   = (const float*)d_in[9];
  const float* Wagg = (const float*)d_in[10];
  const float* bagg = (const float*)d_in[11];
  float* out = (float*)d_out;
  char* ws = (char*)d_ws;

  float* w_ws           = (float*)(ws + OFF_W);
  unsigned short* xb    = (unsigned short*)(ws + OFF_XB);
  unsigned short* w1t   = (unsigned short*)(ws + OFF_W1T);
  unsigned short* w2t   = (unsigned short*)(ws + OFF_W2T);
  unsigned short* w3t   = (unsigned short*)(ws + OFF_W3T);
  unsigned short* waggt = (unsigned short*)(ws + OFF_WAGGT);
  float* wat            = (float*)(ws + OFF_WAT);

  k_transpose<<<dim3(32, 18), 256, 0, stream>>>(W1, w1t, 512, 256);
  k_transpose<<<dim3(8, 18), 256, 0, stream>>>(W2, w2t, 256, 128);
  k_transpose<<<dim3(4, 18), 256, 0, stream>>>(W3, w3t, 128, 128);
  k_transpose<<<dim3(80, 1), 256, 0, stream>>>(Wagg, waggt, 640, 512);
  k_wat<<<36, 256, 0, stream>>>(Wa, wat);
  k_attn<<<4096, 256, 0, stream>>>(X, GV, wat, ba, w_ws, xb);
  k_main<<<256, 512, 0, stream>>>(xb, w_ws, w1t, w2t, w3t, waggt,
                                  b1, b2, b3, bagg, out);
}

// Round 8
// 196.822 us; speedup vs baseline: 3.6377x; 1.4746x over previous
//
#include <hip/hip_runtime.h>

#define NB 16384
#define ND 512
#define NH 128
#define NHH 256
#define NG 18

typedef short s8v __attribute__((ext_vector_type(8)));
typedef __bf16 bf8v __attribute__((ext_vector_type(8)));
typedef float f16v __attribute__((ext_vector_type(16)));
typedef unsigned int u4v __attribute__((ext_vector_type(4)));

static __device__ __forceinline__ unsigned short f2bf(float f) {
  unsigned int u = __builtin_bit_cast(unsigned int, f);
  u += 0x7FFFu + ((u >> 16) & 1u);
  return (unsigned short)(u >> 16);
}

static __device__ __forceinline__ f16v mfma32(s8v a, s8v b, f16v c) {
  return __builtin_amdgcn_mfma_f32_32x32x16_bf16(
      __builtin_bit_cast(bf8v, a), __builtin_bit_cast(bf8v, b), c, 0, 0, 0);
}

static __device__ __forceinline__ f16v zf16() {
  f16v v;
#pragma unroll
  for (int i = 0; i < 16; ++i) v[i] = 0.f;
  return v;
}

// pack W [G][K][N] f32 -> B-fragment-linear bf16 for mfma_32x32x16:
// out[g][((nt*(K/16)+ks)*64 + l)*8 + j] = W[g][ks*16+(l>>5)*8+j][nt*32+(l&31)]
__global__ __launch_bounds__(256) void k_pack(const float* __restrict__ in,
                                              unsigned short* __restrict__ out,
                                              int K, int N) {
  const int g = blockIdx.y;
  const int c = blockIdx.x * 256 + threadIdx.x;
  const int nk = K >> 4;
  const int l = c & 63;
  const int t = c >> 6;
  const int nt = t / nk;
  const int ks = t - nt * nk;
  const int k0 = (ks << 4) + ((l >> 5) << 3);
  const int col = (nt << 5) + (l & 31);
  const float* ip = in + (size_t)g * K * N + (size_t)k0 * N + col;
  u4v pk;
#pragma unroll
  for (int j = 0; j < 4; ++j) {
    float x0 = ip[(size_t)(2 * j) * N];
    float x1 = ip[(size_t)(2 * j + 1) * N];
    pk[j] = (unsigned)f2bf(x0) | ((unsigned)f2bf(x1) << 16);
  }
  *(u4v*)(out + (size_t)g * K * N + ((size_t)c << 3)) = pk;
}

// Wa [512][18] -> WaT [18][512] f32
__global__ __launch_bounds__(256) void k_wat(const float* __restrict__ wa,
                                             float* __restrict__ wat) {
  int tid = blockIdx.x * 256 + threadIdx.x;
  if (tid < NG * ND) {
    int g = tid >> 9, d = tid & (ND - 1);
    wat[tid] = wa[d * NG + g];
  }
}

// attention weights w[B,G] = softmax(X@Wa+ba)*gv, plus X -> bf16
__global__ __launch_bounds__(256) void k_attn(const float* __restrict__ X,
                                              const float* __restrict__ GV,
                                              const float* __restrict__ wat,
                                              const float* __restrict__ ba,
                                              float* __restrict__ w,
                                              unsigned short* __restrict__ xb) {
  __shared__ float wl[NG * ND];
  const int tid = threadIdx.x;
  for (int i = tid; i < NG * ND; i += 256) wl[i] = wat[i];
  __syncthreads();
  const int lane = tid & 63;
  const int row = (blockIdx.x << 2) + (tid >> 6);
  const float* xr = X + (size_t)row * ND + (lane << 3);
  float x[8];
  {
    float4 a = *(const float4*)xr;
    float4 b = *(const float4*)(xr + 4);
    x[0] = a.x; x[1] = a.y; x[2] = a.z; x[3] = a.w;
    x[4] = b.x; x[5] = b.y; x[6] = b.z; x[7] = b.w;
  }
  {
    u4v p;
#pragma unroll
    for (int j = 0; j < 4; ++j)
      p[j] = (unsigned)f2bf(x[2 * j]) | ((unsigned)f2bf(x[2 * j + 1]) << 16);
    *(u4v*)(xb + (size_t)row * ND + (lane << 3)) = p;
  }
  float lg[NG];
#pragma unroll
  for (int g = 0; g < NG; ++g) {
    const float* wr = wl + g * ND + (lane << 3);
    float s = 0.f;
#pragma unroll
    for (int j = 0; j < 8; ++j) s += x[j] * wr[j];
    lg[g] = s;
  }
#pragma unroll
  for (int off = 32; off > 0; off >>= 1) {
#pragma unroll
    for (int g = 0; g < NG; ++g) lg[g] += __shfl_xor(lg[g], off);
  }
  float m = -3.4e38f;
#pragma unroll
  for (int g = 0; g < NG; ++g) { lg[g] += ba[g]; m = fmaxf(m, lg[g]); }
  float s = 0.f;
#pragma unroll
  for (int g = 0; g < NG; ++g) { lg[g] = expf(lg[g] - m); s += lg[g]; }
  float inv = 1.f / s;
  if (lane < NG) {
    float gv = GV[(size_t)row * NG + lane];
    w[(size_t)row * NG + lane] = gv > 0.f ? lg[lane] * inv * gv : 0.f;
  }
}

// fused experts + aggregation. 1 block = 64 rows, 8 waves, mfma 32x32x16.
// LDS tiles in A-fragment-linear layout: [mtile][kstep][lane*16B] -> conflict-free reads.
__global__ __launch_bounds__(512, 2) void k_main(
    const unsigned short* __restrict__ xb,    // [B][512] bf16 (row-linear)
    const float* __restrict__ wbg,            // [B][18]
    const unsigned short* __restrict__ w1p,   // packed [18][512x256]
    const unsigned short* __restrict__ w2p,   // packed [18][256x128]
    const unsigned short* __restrict__ w3p,   // packed [18][128x128]
    const unsigned short* __restrict__ w4p,   // packed [640x512]
    const float* __restrict__ b1, const float* __restrict__ b2,
    const float* __restrict__ b3, const float* __restrict__ bagg,
    float* __restrict__ out) {
  __shared__ __align__(16) char smem[119808];
  char* const XT = smem;                      // [2][32][1024] = 64KB
  char* const H1 = smem + 65536;              // [2][16][1024] = 32KB
  char* const H2 = smem + 98304;              // [2][8][1024]  = 16KB
  float* const WL = (float*)(smem + 114688);  // [64][20]

  const int tid = threadIdx.x;
  const int row0 = blockIdx.x << 6;
  const int wid = tid >> 6, lane = tid & 63;
  const int l31 = lane & 31, lh = lane >> 5;

  // ---- stage XT in fragment-linear order (scatter-read global, linear LDS write)
#pragma unroll
  for (int i = 0; i < 8; ++i) {
    int ck = (i << 9) + tid;                 // chunk 0..4095
    int mt = ck >> 11, ks = (ck >> 6) & 31, l = ck & 63;
    int grow = row0 + (mt << 5) + (l & 31);
    int col8 = (ks << 1) + (l >> 5);
    *(u4v*)(XT + (ck << 4)) =
        *(const u4v*)(xb + ((size_t)grow << 9) + (col8 << 3));
  }
  for (int i = tid; i < 64 * NG; i += 512) {
    int r = i / NG, g = i - r * NG;
    WL[r * 20 + g] = wbg[(size_t)(row0 + r) * NG + g];
  }

  // wave tile assignment
  const int nt2 = wid & 3, mt2 = wid >> 2;   // GEMM2/3 tile
  // packed-B per-wave bases (element offsets)
  const unsigned short* const bp1 = w1p + (wid << 14) + (lane << 3);
  const unsigned short* const bp2 = w2p + (nt2 << 13) + (lane << 3);
  const unsigned short* const bp3 = w3p + (nt2 << 12) + (lane << 3);
  const unsigned short* const bp4a = w4p + (size_t)wid * 20480 + (lane << 3);
  const unsigned short* const bp4b = w4p + (size_t)(wid + 8) * 20480 + (lane << 3);

  // prefetch GEMM1 g=0 ks=0..3 B (drains under staging barrier)
  s8v bq[4];
#pragma unroll
  for (int i = 0; i < 4; ++i) bq[i] = *(const s8v*)(bp1 + (i << 9));

  f16v racc = zf16();
  __syncthreads();

  for (int g = 0; g < NG; ++g) {
    const unsigned short* const bp1g = bp1 + (size_t)g * 131072;
    // ---------- GEMM1: h1 = relu(X @ W1[g] + b1[g])  [64,256] ----------
    f16v acc1[2][2];
    acc1[0][0] = zf16(); acc1[0][1] = zf16();
    acc1[1][0] = zf16(); acc1[1][1] = zf16();
#pragma unroll
    for (int ks = 0; ks < 32; ++ks) {
      s8v bn;
      const bool havenext = (ks < 28) || (g + 1 < NG);
      if (havenext) {
        size_t off = (ks < 28) ? (size_t)((ks + 4) << 9)
                               : (size_t)131072 + ((ks - 28) << 9);
        bn = *(const s8v*)(bp1g + off);
      }
      s8v a0 = *(const s8v*)(XT + (ks << 10) + (lane << 4));
      s8v a1 = *(const s8v*)(XT + 32768 + (ks << 10) + (lane << 4));
      acc1[0][ks & 1] = mfma32(a0, bq[ks & 3], acc1[0][ks & 1]);
      acc1[1][ks & 1] = mfma32(a1, bq[ks & 3], acc1[1][ks & 1]);
      if (havenext) bq[ks & 3] = bn;
    }
    {
      const float bv1 = b1[(g << 8) + (wid << 5) + l31];
      const int gcol = (wid << 5) + l31;
      const int cbase = ((gcol >> 4) << 10) + ((((gcol >> 3) & 1) << 5) << 4) +
                        ((gcol & 7) << 1);
#pragma unroll
      for (int mt = 0; mt < 2; ++mt)
#pragma unroll
        for (int r = 0; r < 16; ++r) {
          const int rl = (r & 3) + ((r >> 2) << 3) + (lh << 2);
          float v = fmaxf(acc1[mt][0][r] + acc1[mt][1][r] + bv1, 0.f);
          *(unsigned short*)(H1 + (mt << 14) + cbase + (rl << 4)) = f2bf(v);
        }
    }
    // hoist ALL GEMM2 B-fragments + bias across the barrier
    const unsigned short* const bp2g = bp2 + ((size_t)g << 15);
    s8v b2f[16];
#pragma unroll
    for (int ks = 0; ks < 16; ++ks) b2f[ks] = *(const s8v*)(bp2g + (ks << 9));
    const float bv2 = b2[(g << 7) + (nt2 << 5) + l31];
    __syncthreads();

    // ---------- GEMM2: h2 = relu(h1 @ W2[g] + b2[g])  [64,128] ----------
    f16v acc2a = zf16(), acc2b = zf16();
#pragma unroll
    for (int ks = 0; ks < 16; ks += 2) {
      s8v a0 = *(const s8v*)(H1 + (mt2 << 14) + (ks << 10) + (lane << 4));
      s8v a1 = *(const s8v*)(H1 + (mt2 << 14) + ((ks + 1) << 10) + (lane << 4));
      acc2a = mfma32(a0, b2f[ks], acc2a);
      acc2b = mfma32(a1, b2f[ks + 1], acc2b);
    }
    {
      const int gcol = (nt2 << 5) + l31;
      const int cbase = ((gcol >> 4) << 10) + ((((gcol >> 3) & 1) << 5) << 4) +
                        ((gcol & 7) << 1);
#pragma unroll
      for (int r = 0; r < 16; ++r) {
        const int rl = (r & 3) + ((r >> 2) << 3) + (lh << 2);
        float v = fmaxf(acc2a[r] + acc2b[r] + bv2, 0.f);
        *(unsigned short*)(H2 + (mt2 << 13) + cbase + (rl << 4)) = f2bf(v);
      }
    }
    // hoist ALL GEMM3 B-fragments + bias across the barrier
    const unsigned short* const bp3g = bp3 + ((size_t)g << 14);
    s8v b3f[8];
#pragma unroll
    for (int ks = 0; ks < 8; ++ks) b3f[ks] = *(const s8v*)(bp3g + (ks << 9));
    const float bv3 = b3[(g << 7) + (nt2 << 5) + l31];
    __syncthreads();

    // ---------- GEMM3: h3 = h2 @ W3[g] + b3[g]; racc += w*h3 ----------
    f16v acc3a = zf16(), acc3b = zf16();
#pragma unroll
    for (int ks = 0; ks < 8; ks += 2) {
      s8v a0 = *(const s8v*)(H2 + (mt2 << 13) + (ks << 10) + (lane << 4));
      s8v a1 = *(const s8v*)(H2 + (mt2 << 13) + ((ks + 1) << 10) + (lane << 4));
      acc3a = mfma32(a0, b3f[ks], acc3a);
      acc3b = mfma32(a1, b3f[ks + 1], acc3b);
    }
#pragma unroll
    for (int r = 0; r < 16; ++r) {
      const int rl = (r & 3) + ((r >> 2) << 3) + (lh << 2);
      const int grow = (mt2 << 5) + rl;
      racc[r] += WL[grow * 20 + g] * (acc3a[r] + acc3b[r] + bv3);
    }
  }

  // prefetch GEMM4 ks=0,1 B for both ntiles (fly across the barriers)
  s8v bq4[2][2];
#pragma unroll
  for (int k = 0; k < 2; ++k) {
    bq4[k][0] = *(const s8v*)(bp4a + (k << 9));
    bq4[k][1] = *(const s8v*)(bp4b + (k << 9));
  }
  __syncthreads();  // all GEMM3 H2 reads done
  {
    const int gcol = (nt2 << 5) + l31;
    const int cbase = ((gcol >> 4) << 10) + ((((gcol >> 3) & 1) << 5) << 4) +
                      ((gcol & 7) << 1);
#pragma unroll
    for (int r = 0; r < 16; ++r) {
      const int rl = (r & 3) + ((r >> 2) << 3) + (lh << 2);
      *(unsigned short*)(H2 + (mt2 << 13) + cbase + (rl << 4)) = f2bf(racc[r]);
    }
  }
  __syncthreads();

  // ---------- GEMM4: out = relu([X | ref] @ Wagg + bagg)  [64,512] ----------
  f16v acc4[2][2];
  acc4[0][0] = zf16(); acc4[0][1] = zf16();
  acc4[1][0] = zf16(); acc4[1][1] = zf16();
#pragma unroll
  for (int ks = 0; ks < 40; ++ks) {
    s8v bn0, bn1;
    if (ks < 38) {
      bn0 = *(const s8v*)(bp4a + ((ks + 2) << 9));
      bn1 = *(const s8v*)(bp4b + ((ks + 2) << 9));
    }
    s8v a0, a1;
    if (ks < 32) {
      a0 = *(const s8v*)(XT + (ks << 10) + (lane << 4));
      a1 = *(const s8v*)(XT + 32768 + (ks << 10) + (lane << 4));
    } else {
      a0 = *(const s8v*)(H2 + ((ks - 32) << 10) + (lane << 4));
      a1 = *(const s8v*)(H2 + 8192 + ((ks - 32) << 10) + (lane << 4));
    }
    acc4[0][0] = mfma32(a0, bq4[ks & 1][0], acc4[0][0]);
    acc4[1][0] = mfma32(a1, bq4[ks & 1][0], acc4[1][0]);
    acc4[0][1] = mfma32(a0, bq4[ks & 1][1], acc4[0][1]);
    acc4[1][1] = mfma32(a1, bq4[ks & 1][1], acc4[1][1]);
    if (ks < 38) { bq4[ks & 1][0] = bn0; bq4[ks & 1][1] = bn1; }
  }
  {
    const float bv4a = bagg[(wid << 5) + l31];
    const float bv4b = bagg[((wid + 8) << 5) + l31];
#pragma unroll
    for (int mt = 0; mt < 2; ++mt)
#pragma unroll
      for (int r = 0; r < 16; ++r) {
        const int rl = (r & 3) + ((r >> 2) << 3) + (lh << 2);
        const size_t rbase = (size_t)(row0 + (mt << 5) + rl) << 9;
        out[rbase + (wid << 5) + l31] = fmaxf(acc4[mt][0][r] + bv4a, 0.f);
        out[rbase + ((wid + 8) << 5) + l31] = fmaxf(acc4[mt][1][r] + bv4b, 0.f);
      }
  }
}

// ---------------- workspace layout (bytes) ----------------
#define OFF_W     0u          // w[B][18] f32        : 1179648
#define OFF_XB    1179648u    // xb[B][512] bf16     : 16777216
#define OFF_W1P   17956864u   // packed W1           : 4718592
#define OFF_W2P   22675456u   // packed W2           : 1179648
#define OFF_W3P   23855104u   // packed W3           : 589824
#define OFF_W4P   24444928u   // packed Wagg         : 655360
#define OFF_WAT   25100288u   // [18][512] f32       : 36864  (end 25137152)

extern "C" void kernel_launch(void* const* d_in, const int* in_sizes, int n_in,
                              void* d_out, int out_size, void* d_ws, size_t ws_size,
                              hipStream_t stream) {
  const float* X    = (const float*)d_in[0];
  const float* GV   = (const float*)d_in[1];
  const float* W1   = (const float*)d_in[2];
  const float* b1   = (const float*)d_in[3];
  const float* W2   = (const float*)d_in[4];
  const float* b2   = (const float*)d_in[5];
  const float* W3   = (const float*)d_in[6];
  const float* b3   = (const float*)d_in[7];
  const float* Wa   = (const float*)d_in[8];
  const float* ba   = (const float*)d_in[9];
  const float* Wagg = (const float*)d_in[10];
  const float* bagg = (const float*)d_in[11];
  float* out = (float*)d_out;
  char* ws = (char*)d_ws;

  float* w_ws           = (float*)(ws + OFF_W);
  unsigned short* xb    = (unsigned short*)(ws + OFF_XB);
  unsigned short* w1p   = (unsigned short*)(ws + OFF_W1P);
  unsigned short* w2p   = (unsigned short*)(ws + OFF_W2P);
  unsigned short* w3p   = (unsigned short*)(ws + OFF_W3P);
  unsigned short* w4p   = (unsigned short*)(ws + OFF_W4P);
  float* wat            = (float*)(ws + OFF_WAT);

  k_pack<<<dim3(64, 18), 256, 0, stream>>>(W1, w1p, 512, 256);
  k_pack<<<dim3(16, 18), 256, 0, stream>>>(W2, w2p, 256, 128);
  k_pack<<<dim3(8, 18), 256, 0, stream>>>(W3, w3p, 128, 128);
  k_pack<<<dim3(160, 1), 256, 0, stream>>>(Wagg, w4p, 640, 512);
  k_wat<<<36, 256, 0, stream>>>(Wa, wat);
  k_attn<<<4096, 256, 0, stream>>>(X, GV, wat, ba, w_ws, xb);
  k_main<<<256, 512, 0, stream>>>(xb, w_ws, w1p, w2p, w3p, w4p,
                                  b1, b2, b3, bagg, out);
}